// Round 1
// baseline (418.948 us; speedup 1.0000x reference)
//
#include <hip/hip_runtime.h>
#include <math.h>

#define N_SLOTS 524288
#define DIM_MEM 128
#define DIM_IN 1024
#define NFACT 138
#define EPSF 1e-8f

// ---- streaming geometry (new path) ----
#define SB 2048                 // blocks for k_score / k_readout
#define SIT 32                  // iters per block: SB * SIT * 8 == N_SLOTS

// ---- old fused-path geometry (fallback) ----
#define CPB 4
#define ROWS_PC 64
#define NPAIR 70
#define PAD 33

// ws layout (new path):
//   0       : float factors[138]   (zeroed)
//   1024    : float derived[16]
//   4096    : float e[N_SLOTS]                  (2 MB, fully written)
//   4096+2M : float scratch[129 * SB]           (~1 MB, fully written)
// ws layout (old path): as before (num @2176, P_acc @2048, zeroed by memset 4096)
#define WS_NEED ((size_t)4096 + (size_t)N_SLOTS * 4 + (size_t)(DIM_MEM + 1) * SB * 4)

// ---- Stage 1: factors = x @ W + b  (1024 x 138) ----
__global__ __launch_bounds__(256) void k_factors(const float* __restrict__ x,
                                                 const float* __restrict__ W,
                                                 const float* __restrict__ b,
                                                 float* __restrict__ factors) {
    int j = threadIdx.x;
    int i0 = blockIdx.x * 32;
    if (j < NFACT) {
        float acc = 0.f;
        #pragma unroll 8
        for (int i = i0; i < i0 + 32; ++i)
            acc = fmaf(x[i], W[(size_t)i * NFACT + j], acc);
        if (blockIdx.x == 0) acc += b[j];
        atomicAdd(&factors[j], acc);
    }
}

// ---- Stage 2: derived scalars ----
// gate = softmax over ONE element == 1.0 exactly -> previous_weighting dead.
// Content-softmax denominator cancels in (t/S)^sh / sum(...), never computed.
__global__ void k_derived(const float* __restrict__ f, float* __restrict__ d) {
    int l = threadIdx.x;            // 64 threads
    float v = f[l] * f[l] + f[l + 64] * f[l + 64];
    for (int off = 32; off; off >>= 1) v += __shfl_xor(v, off, 64);
    if (l == 0) {
        float key_norm = fmaxf(sqrtf(v), EPSF);
        d[0] = f[128] / key_norm;
        float m = f[130];
        for (int j = 1; j < 7; ++j) m = fmaxf(m, f[130 + j]);
        float e[7], s = 0.f;
        for (int j = 0; j < 7; ++j) { e[j] = expf(f[130 + j] - m); s += e[j]; }
        for (int j = 0; j < 7; ++j) d[1 + j] = e[j] / s;
        d[8] = fmaxf(f[137], 0.f) + 1.f;
    }
}

// ---- NEW Pass 1: e[i] = exp(d0 * dot(mem_i, key) / max(||mem_i||, eps)) ----
// Pure stream: half-wave (32 lanes) per row, float4 loads, butterfly reduce.
// No LDS, no barriers, ~25 VGPRs -> max occupancy.
__global__ __launch_bounds__(256) void k_score(const float* __restrict__ mem,
                                               const float* __restrict__ keyv,
                                               const float* __restrict__ der,
                                               float* __restrict__ e_out) {
    const int tid  = threadIdx.x;
    const int lane = tid & 31;
    const int hw   = tid >> 5;                   // 8 half-waves -> 8 rows/iter
    const float4* __restrict__ mem4 = (const float4*)mem;
    const float4 k4 = ((const float4*)keyv)[lane];
    const float d0 = der[0];

    int r = blockIdx.x * (SIT * 8) + hw;         // contiguous 256-row span/block
    const float4* __restrict__ p = mem4 + (size_t)r * 32 + lane;

    #pragma unroll 4
    for (int it = 0; it < SIT; ++it, r += 8, p += 8 * 32) {
        float4 m = *p;
        float dp = m.x * k4.x + m.y * k4.y + m.z * k4.z + m.w * k4.w;
        float np = m.x * m.x + m.y * m.y + m.z * m.z + m.w * m.w;
        #pragma unroll
        for (int off = 16; off; off >>= 1) {
            dp += __shfl_xor(dp, off, 32);
            np += __shfl_xor(np, off, 32);
        }
        if (lane == 0)
            e_out[r] = __expf(d0 * dp / fmaxf(sqrtf(np), EPSF));
    }
}

// ---- NEW Pass 2: w_i = (sum_d sw[d]*e[i+d-3])^sharp; acc += w_i*row_i ----
// Pure stream. e-stencil loads are half-wave-uniform (L1 broadcast hits).
// Per-block partials to global scratch (column-major) -> ZERO atomics.
__global__ __launch_bounds__(256) void k_readout(const float* __restrict__ mem,
                                                 const float* __restrict__ e,
                                                 const float* __restrict__ der,
                                                 float* __restrict__ sc) {
    __shared__ float colpart[8][DIM_MEM];
    __shared__ float psum[8];

    const int tid  = threadIdx.x;
    const int lane = tid & 31;
    const int hw   = tid >> 5;
    const float4* __restrict__ mem4 = (const float4*)mem;
    const float sharp = der[8];
    float sw[7];
    #pragma unroll
    for (int d = 0; d < 7; ++d) sw[d] = der[1 + d];

    float4 acc = make_float4(0.f, 0.f, 0.f, 0.f);
    float wsum = 0.f;

    int r = blockIdx.x * (SIT * 8) + hw;
    const float4* __restrict__ p = mem4 + (size_t)r * 32 + lane;

    #pragma unroll 2
    for (int it = 0; it < SIT; ++it, r += 8, p += 8 * 32) {
        float4 m = *p;
        float t = 0.f;
        #pragma unroll
        for (int d = 0; d < 7; ++d)
            t = fmaf(sw[d], e[(r + d - 3) & (N_SLOTS - 1)], t);
        float w = __expf(sharp * __logf(t));     // t > 0 always
        acc.x = fmaf(w, m.x, acc.x);
        acc.y = fmaf(w, m.y, acc.y);
        acc.z = fmaf(w, m.z, acc.z);
        acc.w = fmaf(w, m.w, acc.w);
        if (lane == 0) wsum += w;                // one lane owns the row's w
    }

    // Block epilogue: reduce 8 half-wave partials, plain stores (no atomics)
    ((float4*)colpart[hw])[lane] = acc;
    if (lane == 0) psum[hw] = wsum;
    __syncthreads();
    if (tid < DIM_MEM) {
        float s = 0.f;
        #pragma unroll
        for (int h = 0; h < 8; ++h) s += colpart[h][tid];
        sc[(size_t)tid * SB + blockIdx.x] = s;   // column-major: coalesced reduce
    }
    if (tid == 0) {
        float s = 0.f;
        #pragma unroll
        for (int h = 0; h < 8; ++h) s += psum[h];
        sc[(size_t)DIM_MEM * SB + blockIdx.x] = s;
    }
}

// ---- NEW Stage 4: reduce per-block partials, out = num/P fused ----
__global__ void k_reduce(const float* __restrict__ sc, float* __restrict__ out) {
    __shared__ float red[8];
    const int c = blockIdx.x;                    // one block per output column
    const int t = threadIdx.x;
    float s = 0.f, pv = 0.f;
    for (int b = t; b < SB; b += 256) {
        s  += sc[(size_t)c * SB + b];
        pv += sc[(size_t)DIM_MEM * SB + b];
    }
    #pragma unroll
    for (int off = 32; off; off >>= 1) {
        s  += __shfl_xor(s, off, 64);
        pv += __shfl_xor(pv, off, 64);
    }
    const int w = t >> 6;
    if ((t & 63) == 0) { red[w * 2] = s; red[w * 2 + 1] = pv; }
    __syncthreads();
    if (t == 0) {
        float S = 0.f, P = 0.f;
        #pragma unroll
        for (int i = 0; i < 4; ++i) { S += red[i * 2]; P += red[i * 2 + 1]; }
        out[c] = S / P;
    }
}

// ================= OLD fused path (fallback if workspace too small) ==========
__global__ __launch_bounds__(256) void k_main(const float* __restrict__ mem,
                                              const float* __restrict__ keyv,
                                              const float* __restrict__ der,
                                              float* __restrict__ num,
                                              double* __restrict__ P_acc) {
    __shared__ float part[2 * NPAIR * PAD];
    __shared__ float sums[2 * NPAIR];
    __shared__ float e_sh[NPAIR];
    __shared__ float w_sh[ROWS_PC];
    __shared__ float colpart[8][DIM_MEM];
    __shared__ float psum[8];

    const int tid  = threadIdx.x;
    const int lane = tid & 31;
    const int hw   = tid >> 5;
    const float4* mem4 = (const float4*)mem;
    const float4 k4 = ((const float4*)keyv)[lane];
    const float d0 = der[0];
    const float sharp = der[8];
    float sw[7];
    #pragma unroll
    for (int d = 0; d < 7; ++d) sw[d] = der[1 + d];

    float4 acc = make_float4(0.f, 0.f, 0.f, 0.f);
    float wsum = 0.f;

    for (int c = 0; c < CPB; ++c) {
        const int r0 = blockIdx.x * (CPB * ROWS_PC) + c * ROWS_PC;
        const int rbase = r0 + hw * 8;
        float4 row[8];
        #pragma unroll
        for (int j = 0; j < 8; ++j)
            row[j] = mem4[(size_t)(rbase + j) * 32 + lane];
        #pragma unroll
        for (int j = 0; j < 8; ++j) {
            float dp = row[j].x * k4.x + row[j].y * k4.y + row[j].z * k4.z + row[j].w * k4.w;
            float np = row[j].x * row[j].x + row[j].y * row[j].y + row[j].z * row[j].z + row[j].w * row[j].w;
            int pp = 3 + hw * 8 + j;
            part[(pp * 2 + 0) * PAD + lane] = dp;
            part[(pp * 2 + 1) * PAD + lane] = np;
        }
        if (hw < 6) {
            int hr = (hw < 3) ? (r0 - 3 + hw) : (r0 + ROWS_PC + (hw - 3));
            hr &= (N_SLOTS - 1);
            int pp = (hw < 3) ? hw : (64 + hw);
            float4 m4 = mem4[(size_t)hr * 32 + lane];
            part[(pp * 2 + 0) * PAD + lane] =
                m4.x * k4.x + m4.y * k4.y + m4.z * k4.z + m4.w * k4.w;
            part[(pp * 2 + 1) * PAD + lane] =
                m4.x * m4.x + m4.y * m4.y + m4.z * m4.z + m4.w * m4.w;
        }
        __syncthreads();
        if (tid < 2 * NPAIR) {
            float s = 0.f;
            #pragma unroll
            for (int l = 0; l < 32; ++l) s += part[tid * PAD + l];
            sums[tid] = s;
        }
        __syncthreads();
        if (tid < NPAIR) {
            float dot = sums[tid * 2], n2 = sums[tid * 2 + 1];
            e_sh[tid] = __expf(d0 * dot / fmaxf(sqrtf(n2), EPSF));
        }
        __syncthreads();
        if (tid < ROWS_PC) {
            float t = 0.f;
            #pragma unroll
            for (int d = 0; d < 7; ++d) t = fmaf(sw[d], e_sh[tid + d], t);
            w_sh[tid] = __expf(sharp * __logf(t));
        }
        __syncthreads();
        #pragma unroll
        for (int j = 0; j < 8; ++j) {
            float w = w_sh[hw * 8 + j];
            acc.x = fmaf(w, row[j].x, acc.x);
            acc.y = fmaf(w, row[j].y, acc.y);
            acc.z = fmaf(w, row[j].z, acc.z);
            acc.w = fmaf(w, row[j].w, acc.w);
            wsum += w;
        }
        __syncthreads();
    }

    ((float4*)colpart[hw])[lane] = acc;
    if (lane == 0) psum[hw] = wsum;
    __syncthreads();
    if (tid < DIM_MEM) {
        float s = 0.f;
        #pragma unroll
        for (int h = 0; h < 8; ++h) s += colpart[h][tid];
        atomicAdd(&num[tid], s);
    }
    if (tid == 0) {
        float s = 0.f;
        #pragma unroll
        for (int h = 0; h < 8; ++h) s += psum[h];
        atomicAdd(P_acc, (double)s);
    }
}

__global__ void k_final(const float* __restrict__ num,
                        const double* __restrict__ P_acc,
                        float* __restrict__ out) {
    out[threadIdx.x] = num[threadIdx.x] / (float)(*P_acc);
}
// ============================================================================

extern "C" void kernel_launch(void* const* d_in, const int* in_sizes, int n_in,
                              void* d_out, int out_size, void* d_ws, size_t ws_size,
                              hipStream_t stream) {
    const float* x   = (const float*)d_in[0];   // input_from_controller (1024)
    // d_in[1] = previous_weighting: unused (gate == 1.0 exactly)
    const float* mem = (const float*)d_in[2];   // memory (N_SLOTS*128)
    const float* W   = (const float*)d_in[3];   // W_wf (1024*138)
    const float* b   = (const float*)d_in[4];   // b_wf (138)
    float* out = (float*)d_out;

    char* ws = (char*)d_ws;
    float* factors = (float*)ws;
    float* derived = (float*)(ws + 1024);

    hipMemsetAsync(ws, 0, 4096, stream);

    k_factors<<<DIM_IN / 32, 256, 0, stream>>>(x, W, b, factors);
    k_derived<<<1, 64, 0, stream>>>(factors, derived);

    if (ws_size >= WS_NEED) {
        // streaming two-pass path: no barriers in hot loops, no atomics
        float* e  = (float*)(ws + 4096);
        float* sc = (float*)(ws + 4096 + (size_t)N_SLOTS * 4);
        k_score<<<SB, 256, 0, stream>>>(mem, factors, derived, e);
        k_readout<<<SB, 256, 0, stream>>>(mem, e, derived, sc);
        k_reduce<<<DIM_MEM, 256, 0, stream>>>(sc, out);
    } else {
        // fallback: previous fused kernel
        double* P_acc = (double*)(ws + 2048);
        float*  num   = (float*)(ws + 2176);
        k_main<<<N_SLOTS / (CPB * ROWS_PC), 256, 0, stream>>>(mem, factors, derived, num, P_acc);
        k_final<<<1, DIM_MEM, 0, stream>>>(num, P_acc, out);
    }
}

// Round 2
// 381.474 us; speedup vs baseline: 1.0982x; 1.0982x over previous
//
#include <hip/hip_runtime.h>
#include <math.h>

#define N_SLOTS 524288
#define DIM_MEM 128
#define DIM_IN 1024
#define NFACT 138
#define EPSF 1e-8f

#define RPB 256                  // rows per block (k_fused)
#define CHUNK 64                 // rows per chunk
#define NCH (RPB / CHUNK)        // 4 chunks
#define FB (N_SLOTS / RPB)       // 2048 blocks

// ws layout:
//   0    : float factors[138]        (fully written by k_factors, no memset needed)
//   4096 : float sc[129 * FB]        (fully written by k_fused)
#define WS_NEED ((size_t)4096 + (size_t)(DIM_MEM + 1) * FB * 4)

// ---- Stage 1: factors = x @ W + b.  One block per output column, no atomics.
// W column reads are strided (552 B) but W is 565 KB -> L2-resident after warmup;
// 138 blocks, latency-bound, ~3-5 us.
__global__ __launch_bounds__(256) void k_factors(const float* __restrict__ x,
                                                 const float* __restrict__ W,
                                                 const float* __restrict__ b,
                                                 float* __restrict__ factors) {
    __shared__ float wred[4];
    const int j = blockIdx.x;           // 0..137
    const int t = threadIdx.x;
    float acc = 0.f;
    #pragma unroll
    for (int i = t; i < DIM_IN; i += 256)
        acc = fmaf(x[i], W[(size_t)i * NFACT + j], acc);
    #pragma unroll
    for (int off = 32; off; off >>= 1) acc += __shfl_xor(acc, off, 64);
    if ((t & 63) == 0) wred[t >> 6] = acc;
    __syncthreads();
    if (t == 0)
        factors[j] = wred[0] + wred[1] + wred[2] + wred[3] + b[j];
}

// ---- Stage 2: fused single pass.
// gate = softmax over ONE element == 1.0 -> previous_weighting is dead.
// Content-softmax denominator cancels in (t/S)^sh / sum(...), never computed.
// Derived scalars recomputed per block (cheap, saves a launch).
// Per-row score via in-register half-wave butterfly (no LDS transpose).
// Next chunk's rows prefetched into registers before the barriers.
// Epilogue: per-block partials to global scratch -> ZERO atomics.
__global__ __launch_bounds__(256) void k_fused(const float* __restrict__ mem,
                                               const float* __restrict__ f,
                                               float* __restrict__ sc) {
    __shared__ float d_sh[12];
    __shared__ float e_sh[CHUNK + 8];        // [0..2] left halo, [3..66] own, [67..69] right halo
    __shared__ float w_sh[CHUNK];
    __shared__ float colpart[8][DIM_MEM];
    __shared__ float psum[8];

    const int tid  = threadIdx.x;
    const int lane = tid & 31;               // half-wave lane: 4 columns each
    const int hw   = tid >> 5;               // 8 half-waves

    // derived scalars (wave 0 only)
    if (tid < 64) {
        float fl = f[tid], fh = f[tid + 64];
        float v = fl * fl + fh * fh;
        #pragma unroll
        for (int off = 32; off; off >>= 1) v += __shfl_xor(v, off, 64);
        if (tid == 0) {
            float key_norm = fmaxf(sqrtf(v), EPSF);
            d_sh[0] = f[128] / key_norm;                 // key_s / key_norm
            float m = f[130];
            #pragma unroll
            for (int q = 1; q < 7; ++q) m = fmaxf(m, f[130 + q]);
            float e[7], s = 0.f;
            #pragma unroll
            for (int q = 0; q < 7; ++q) { e[q] = __expf(f[130 + q] - m); s += e[q]; }
            #pragma unroll
            for (int q = 0; q < 7; ++q) d_sh[1 + q] = e[q] / s;   // shift softmax
            d_sh[8] = fmaxf(f[137], 0.f) + 1.f;                   // sharpening
        }
    }
    __syncthreads();

    const float4* __restrict__ mem4 = (const float4*)mem;
    const float4 k4 = ((const float4*)f)[lane];          // key = factors[0..127]
    const float d0 = d_sh[0];
    const float sharp = d_sh[8];
    float sw[7];
    #pragma unroll
    for (int d = 0; d < 7; ++d) sw[d] = d_sh[1 + d];

    float4 acc = make_float4(0.f, 0.f, 0.f, 0.f);
    float wsum = 0.f;
    const int base = blockIdx.x * RPB;

    float4 row[2][8];
    #pragma unroll
    for (int j = 0; j < 8; ++j)                          // preload chunk 0
        row[0][j] = mem4[(size_t)(base + hw * 8 + j) * 32 + lane];

    #pragma unroll
    for (int c = 0; c < NCH; ++c) {
        const int cur = c & 1;
        const int nxt = cur ^ 1;
        const int r0 = base + c * CHUNK;

        // Phase A: scores for own 8 rows (in-register butterfly reduce)
        #pragma unroll
        for (int j = 0; j < 8; ++j) {
            float4 m = row[cur][j];
            float dp = m.x * k4.x + m.y * k4.y + m.z * k4.z + m.w * k4.w;
            float np = m.x * m.x + m.y * m.y + m.z * m.z + m.w * m.w;
            #pragma unroll
            for (int off = 16; off; off >>= 1) {
                dp += __shfl_xor(dp, off, 32);
                np += __shfl_xor(np, off, 32);
            }
            if (lane == 0)
                e_sh[3 + hw * 8 + j] = __expf(d0 * dp / fmaxf(sqrtf(np), EPSF));
        }
        // halo rows: 3 left + 3 right (circular), one per half-wave 0..5
        if (hw < 6) {
            int hr = (hw < 3) ? (r0 - 3 + hw) : (r0 + CHUNK + (hw - 3));
            hr &= (N_SLOTS - 1);
            const int p = (hw < 3) ? hw : (CHUNK + hw);  // 0..2, 67..69
            float4 m = mem4[(size_t)hr * 32 + lane];
            float dp = m.x * k4.x + m.y * k4.y + m.z * k4.z + m.w * k4.w;
            float np = m.x * m.x + m.y * m.y + m.z * m.z + m.w * m.w;
            #pragma unroll
            for (int off = 16; off; off >>= 1) {
                dp += __shfl_xor(dp, off, 32);
                np += __shfl_xor(np, off, 32);
            }
            if (lane == 0)
                e_sh[p] = __expf(d0 * dp / fmaxf(sqrtf(np), EPSF));
        }
        // prefetch next chunk's rows (stays in flight across the barriers)
        if (c + 1 < NCH) {
            const int nb = r0 + CHUNK + hw * 8;
            #pragma unroll
            for (int j = 0; j < 8; ++j)
                row[nxt][j] = mem4[(size_t)(nb + j) * 32 + lane];
        }
        __syncthreads();

        // Phase B: 7-tap stencil + sharpening (one thread per row)
        if (tid < CHUNK) {
            float t = 0.f;
            #pragma unroll
            for (int d = 0; d < 7; ++d) t = fmaf(sw[d], e_sh[tid + d], t);
            w_sh[tid] = __expf(sharp * __logf(t));       // t > 0 always
        }
        __syncthreads();

        // Phase C: accumulate w * row from registers
        #pragma unroll
        for (int j = 0; j < 8; ++j) {
            float w = w_sh[hw * 8 + j];                  // half-wave-uniform broadcast
            acc.x = fmaf(w, row[cur][j].x, acc.x);
            acc.y = fmaf(w, row[cur][j].y, acc.y);
            acc.z = fmaf(w, row[cur][j].z, acc.z);
            acc.w = fmaf(w, row[cur][j].w, acc.w);
            wsum += w;
        }
        // no trailing barrier needed: next A's e_sh writes are safe (all waves
        // passed this chunk's second barrier before any wave reaches next A's
        // first barrier; e_sh readers finished before the second barrier).
    }

    // Block epilogue: reduce 8 half-wave partials, plain stores (no atomics)
    ((float4*)colpart[hw])[lane] = acc;
    if (lane == 0) psum[hw] = wsum;
    __syncthreads();
    if (tid < DIM_MEM) {
        float s = 0.f;
        #pragma unroll
        for (int h = 0; h < 8; ++h) s += colpart[h][tid];
        sc[(size_t)tid * FB + blockIdx.x] = s;           // column-major: coalesced reduce
    }
    if (tid == 0) {
        float s = 0.f;
        #pragma unroll
        for (int h = 0; h < 8; ++h) s += psum[h];
        sc[(size_t)DIM_MEM * FB + blockIdx.x] = s;       // P partials
    }
}

// ---- Stage 3: reduce per-block partials, out = num / P fused ----
__global__ void k_reduce(const float* __restrict__ sc, float* __restrict__ out) {
    __shared__ float red[8];
    const int c = blockIdx.x;                            // one block per output column
    const int t = threadIdx.x;
    float s = 0.f, pv = 0.f;
    for (int b = t; b < FB; b += 256) {
        s  += sc[(size_t)c * FB + b];
        pv += sc[(size_t)DIM_MEM * FB + b];
    }
    #pragma unroll
    for (int off = 32; off; off >>= 1) {
        s  += __shfl_xor(s, off, 64);
        pv += __shfl_xor(pv, off, 64);
    }
    const int w = t >> 6;
    if ((t & 63) == 0) { red[w * 2] = s; red[w * 2 + 1] = pv; }
    __syncthreads();
    if (t == 0) {
        float S = 0.f, P = 0.f;
        #pragma unroll
        for (int i = 0; i < 4; ++i) { S += red[i * 2]; P += red[i * 2 + 1]; }
        out[c] = S / P;
    }
}

extern "C" void kernel_launch(void* const* d_in, const int* in_sizes, int n_in,
                              void* d_out, int out_size, void* d_ws, size_t ws_size,
                              hipStream_t stream) {
    (void)in_sizes; (void)n_in; (void)out_size; (void)ws_size;
    const float* x   = (const float*)d_in[0];   // input_from_controller (1024)
    // d_in[1] = previous_weighting: unused (gate == 1.0 exactly)
    const float* mem = (const float*)d_in[2];   // memory (N_SLOTS*128)
    const float* W   = (const float*)d_in[3];   // W_wf (1024*138)
    const float* b   = (const float*)d_in[4];   // b_wf (138)
    float* out = (float*)d_out;

    char*  ws      = (char*)d_ws;
    float* factors = (float*)ws;
    float* sc      = (float*)(ws + 4096);

    // no memset: factors and sc are fully written each call
    k_factors<<<NFACT, 256, 0, stream>>>(x, W, b, factors);
    k_fused<<<FB, 256, 0, stream>>>(mem, factors, sc);
    k_reduce<<<DIM_MEM, 256, 0, stream>>>(sc, out);
}

// Round 4
// 376.384 us; speedup vs baseline: 1.1131x; 1.0135x over previous
//
#include <hip/hip_runtime.h>
#include <math.h>

#define N_SLOTS 524288
#define DIM_MEM 128
#define DIM_IN 1024
#define NFACT 138
#define EPSF 1e-8f

#define RPB 256                  // rows per block (k_fused)
#define CHUNK 64                 // rows per chunk
#define NCH (RPB / CHUNK)        // 4 chunks
#define FB (N_SLOTS / RPB)       // 2048 blocks

typedef float f4 __attribute__((ext_vector_type(4)));

__device__ __forceinline__ float dot4(f4 a, f4 b) {
    f4 t = a * b;
    return (t.x + t.y) + (t.z + t.w);
}

// ws layout:
//   0    : float factors[138]        (fully written by k_factors, no memset needed)
//   4096 : float sc[129 * FB]        (fully written by k_fused)

// ---- Stage 1: factors = x @ W + b.  One block per output column, no atomics.
__global__ __launch_bounds__(256) void k_factors(const float* __restrict__ x,
                                                 const float* __restrict__ W,
                                                 const float* __restrict__ b,
                                                 float* __restrict__ factors) {
    __shared__ float wred[4];
    const int j = blockIdx.x;           // 0..137
    const int t = threadIdx.x;
    float acc = 0.f;
    #pragma unroll
    for (int i = t; i < DIM_IN; i += 256)
        acc = fmaf(x[i], W[(size_t)i * NFACT + j], acc);
    #pragma unroll
    for (int off = 32; off; off >>= 1) acc += __shfl_xor(acc, off, 64);
    if ((t & 63) == 0) wred[t >> 6] = acc;
    __syncthreads();
    if (t == 0)
        factors[j] = wred[0] + wred[1] + wred[2] + wred[3] + b[j];
}

// ---- Stage 2: fused single pass over memory.
// gate = softmax over ONE element == 1.0 -> previous_weighting is dead.
// Content-softmax denominator cancels in (t/S)^sh / sum(...), never computed.
// Quarter-wave (16-lane) row ownership: 4 butterfly levels x 2 vals x 4 rows
// = 32 shuffles/thread/chunk (was 80 with half-wave) -> DS pipe off the
// critical path; memory stream stays the limiter.
__global__ __launch_bounds__(256) void k_fused(const float* __restrict__ mem,
                                               const float* __restrict__ f,
                                               float* __restrict__ sc) {
    __shared__ float d_sh[12];
    __shared__ float e_sh[CHUNK + 8];    // [0..2] left halo, [3..66] own, [67..69] right halo
    __shared__ float w_sh[CHUNK];
    __shared__ float colpart[4][DIM_MEM] __attribute__((aligned(16)));
    __shared__ float psum[4];

    const int tid = threadIdx.x;
    const int sub = tid & 15;            // lane within quarter-wave: 8 columns each
    const int qw  = tid >> 4;            // 16 quarter-wave groups
    const int wv  = tid >> 6;            // wave id 0..3
    const int l6  = tid & 63;

    // derived scalars (wave 0 only)
    if (tid < 64) {
        float fl = f[tid], fh = f[tid + 64];
        float v = fl * fl + fh * fh;
        #pragma unroll
        for (int off = 32; off; off >>= 1) v += __shfl_xor(v, off, 64);
        if (tid == 0) {
            float key_norm = fmaxf(sqrtf(v), EPSF);
            d_sh[0] = f[128] / key_norm;                 // key_s / key_norm
            float m = f[130];
            #pragma unroll
            for (int q = 1; q < 7; ++q) m = fmaxf(m, f[130 + q]);
            float e[7], s = 0.f;
            #pragma unroll
            for (int q = 0; q < 7; ++q) { e[q] = __expf(f[130 + q] - m); s += e[q]; }
            #pragma unroll
            for (int q = 0; q < 7; ++q) d_sh[1 + q] = e[q] / s;   // shift softmax
            d_sh[8] = fmaxf(f[137], 0.f) + 1.f;                   // sharpening
        }
    }

    const f4* __restrict__ mem4 = (const f4*)mem;
    const f4* __restrict__ kf4  = (const f4*)f;
    const f4 ka = kf4[sub];              // key cols [sub*4 .. +3]
    const f4 kb = kf4[16 + sub];         // key cols [64 + sub*4 .. +3]

    const int base = blockIdx.x * RPB;
    f4 row[2][4][2];
    #pragma unroll
    for (int j = 0; j < 4; ++j) {        // preload chunk 0 (before the barrier)
        const size_t rr = (size_t)(base + qw * 4 + j) * 32;
        row[0][j][0] = mem4[rr + sub];
        row[0][j][1] = mem4[rr + 16 + sub];
    }
    __syncthreads();

    const float d0 = d_sh[0];
    const float sharp = d_sh[8];
    float sw[7];
    #pragma unroll
    for (int d = 0; d < 7; ++d) sw[d] = d_sh[1 + d];

    f4 acc0 = {0.f, 0.f, 0.f, 0.f};
    f4 acc1 = {0.f, 0.f, 0.f, 0.f};
    float wsum = 0.f;

    #pragma unroll
    for (int c = 0; c < NCH; ++c) {
        const int cur = c & 1;
        const int nxt = cur ^ 1;
        const int r0 = base + c * CHUNK;

        // issue halo loads early (3 left + 3 right, circular; groups 0..5)
        f4 ha = {0.f,0.f,0.f,0.f}, hb = {0.f,0.f,0.f,0.f};
        int hp = 0;
        if (qw < 6) {
            int hr = (qw < 3) ? (r0 - 3 + qw) : (r0 + CHUNK + (qw - 3));
            hr &= (N_SLOTS - 1);
            hp = (qw < 3) ? qw : (CHUNK + qw);           // 0..2, 67..69
            ha = mem4[(size_t)hr * 32 + sub];
            hb = mem4[(size_t)hr * 32 + 16 + sub];
        }
        // issue next chunk's row loads (stay in flight across the barriers)
        if (c + 1 < NCH) {
            #pragma unroll
            for (int j = 0; j < 4; ++j) {
                const size_t rr = (size_t)(r0 + CHUNK + qw * 4 + j) * 32;
                row[nxt][j][0] = mem4[rr + sub];
                row[nxt][j][1] = mem4[rr + 16 + sub];
            }
        }

        // Phase A: scores for own 4 rows (4-level butterfly within 16 lanes)
        #pragma unroll
        for (int j = 0; j < 4; ++j) {
            float dp = dot4(row[cur][j][0], ka) + dot4(row[cur][j][1], kb);
            float np = dot4(row[cur][j][0], row[cur][j][0])
                     + dot4(row[cur][j][1], row[cur][j][1]);
            #pragma unroll
            for (int off = 1; off <= 8; off <<= 1) {
                dp += __shfl_xor(dp, off, 64);
                np += __shfl_xor(np, off, 64);
            }
            if (sub == 0)
                e_sh[3 + qw * 4 + j] = __expf(d0 * dp / fmaxf(sqrtf(np), EPSF));
        }
        if (qw < 6) {                                    // halo scores
            float dp = dot4(ha, ka) + dot4(hb, kb);
            float np = dot4(ha, ha) + dot4(hb, hb);
            #pragma unroll
            for (int off = 1; off <= 8; off <<= 1) {
                dp += __shfl_xor(dp, off, 64);
                np += __shfl_xor(np, off, 64);
            }
            if (sub == 0)
                e_sh[hp] = __expf(d0 * dp / fmaxf(sqrtf(np), EPSF));
        }
        __syncthreads();

        // Phase B: 7-tap stencil + sharpening (one thread per row)
        if (tid < CHUNK) {
            float t = 0.f;
            #pragma unroll
            for (int d = 0; d < 7; ++d) t = fmaf(sw[d], e_sh[tid + d], t);
            w_sh[tid] = __expf(sharp * __logf(t));       // t > 0 always
        }
        __syncthreads();

        // Phase C: accumulate w * row from registers
        #pragma unroll
        for (int j = 0; j < 4; ++j) {
            const float w = w_sh[qw * 4 + j];            // group-uniform broadcast
            acc0 += w * row[cur][j][0];
            acc1 += w * row[cur][j][1];
        }
        if (sub == 0)
            wsum += w_sh[qw * 4] + w_sh[qw * 4 + 1] + w_sh[qw * 4 + 2] + w_sh[qw * 4 + 3];
        // no trailing barrier: next A's e_sh writes are ordered after this
        // chunk's B-barrier; w_sh next written only after next A-barrier.
    }

    // Epilogue: reduce across the 4 quarter-waves of each wave in registers,
    // then across waves via LDS; plain stores, ZERO atomics.
    #pragma unroll
    for (int off = 16; off <= 32; off <<= 1) {
        acc0.x += __shfl_xor(acc0.x, off, 64);
        acc0.y += __shfl_xor(acc0.y, off, 64);
        acc0.z += __shfl_xor(acc0.z, off, 64);
        acc0.w += __shfl_xor(acc0.w, off, 64);
        acc1.x += __shfl_xor(acc1.x, off, 64);
        acc1.y += __shfl_xor(acc1.y, off, 64);
        acc1.z += __shfl_xor(acc1.z, off, 64);
        acc1.w += __shfl_xor(acc1.w, off, 64);
        wsum   += __shfl_xor(wsum,   off, 64);
    }
    if (l6 < 16) {
        ((f4*)colpart[wv])[l6]      = acc0;              // cols l6*4..+3
        ((f4*)colpart[wv])[16 + l6] = acc1;              // cols 64+l6*4..+3
    }
    if (l6 == 0) psum[wv] = wsum;
    __syncthreads();
    if (tid < DIM_MEM) {
        float s = colpart[0][tid] + colpart[1][tid] + colpart[2][tid] + colpart[3][tid];
        sc[(size_t)tid * FB + blockIdx.x] = s;           // column-major: coalesced reduce
    }
    if (tid == 0)
        sc[(size_t)DIM_MEM * FB + blockIdx.x] = psum[0] + psum[1] + psum[2] + psum[3];
}

// ---- Stage 3: reduce per-block partials, out = num / P fused ----
__global__ void k_reduce(const float* __restrict__ sc, float* __restrict__ out) {
    __shared__ float red[8];
    const int c = blockIdx.x;                            // one block per output column
    const int t = threadIdx.x;
    float s = 0.f, pv = 0.f;
    for (int b = t; b < FB; b += 256) {
        s  += sc[(size_t)c * FB + b];
        pv += sc[(size_t)DIM_MEM * FB + b];
    }
    #pragma unroll
    for (int off = 32; off; off >>= 1) {
        s  += __shfl_xor(s, off, 64);
        pv += __shfl_xor(pv, off, 64);
    }
    const int w = t >> 6;
    if ((t & 63) == 0) { red[w * 2] = s; red[w * 2 + 1] = pv; }
    __syncthreads();
    if (t == 0) {
        float S = 0.f, P = 0.f;
        #pragma unroll
        for (int i = 0; i < 4; ++i) { S += red[i * 2]; P += red[i * 2 + 1]; }
        out[c] = S / P;
    }
}

extern "C" void kernel_launch(void* const* d_in, const int* in_sizes, int n_in,
                              void* d_out, int out_size, void* d_ws, size_t ws_size,
                              hipStream_t stream) {
    (void)in_sizes; (void)n_in; (void)out_size; (void)ws_size;
    const float* x   = (const float*)d_in[0];   // input_from_controller (1024)
    // d_in[1] = previous_weighting: unused (gate == 1.0 exactly)
    const float* mem = (const float*)d_in[2];   // memory (N_SLOTS*128)
    const float* W   = (const float*)d_in[3];   // W_wf (1024*138)
    const float* b   = (const float*)d_in[4];   // b_wf (138)
    float* out = (float*)d_out;

    char*  ws      = (char*)d_ws;
    float* factors = (float*)ws;
    float* sc      = (float*)(ws + 4096);

    // no memset: factors and sc are fully written each call
    k_factors<<<NFACT, 256, 0, stream>>>(x, W, b, factors);
    k_fused<<<FB, 256, 0, stream>>>(mem, factors, sc);
    k_reduce<<<DIM_MEM, 256, 0, stream>>>(sc, out);
}